// Round 1
// 255.088 us; speedup vs baseline: 1.0851x; 1.0851x over previous
//
#include <hip/hip_runtime.h>
#include <hip/hip_bf16.h>
#include <stdint.h>

#define BATCH   4096
#define IN_DIM  1024
#define OUT_DIM 1024
#define GRID_G  8
#define K8      16384            // spline K: 16 planes (8 cos + 8 sin) * 1024
#define KB      1024             // base K (silu plane)
#define SPLIT8  4                // spline split-K: 32 iters of BK=128 bytes
#define WSCALE  256.0f           // spline weights scaled into e4m3 range

typedef __bf16 bf16x8 __attribute__((ext_vector_type(8)));
typedef __bf16 bf16x4 __attribute__((ext_vector_type(4)));
typedef float  f32x4  __attribute__((ext_vector_type(4)));
typedef int    i32x4  __attribute__((ext_vector_type(4)));
typedef int    i32x8  __attribute__((ext_vector_type(8)));

// ---------------------------------------------------------------------------
// prep_feat: features for A. 16 consecutive i per thread.
//   - silu(x) -> Ab (bf16)
//   - cos(g x), sin(g x) g=1..8 -> A8 fp8 planes [b, p*1024+i] (p<8 cos, p>=8 sin)
//   - also zeroes C (64 B/thread == exactly B*O floats), replacing hipMemsetAsync
// Changes vs prior version: value-returning __sinf/__cosf (no address-taken
// locals through OCML), silu via v_rcp instead of exact fp32 div (kills the
// VCC-serialized div expansion), 16 B dwordx4 stores for all fp8 planes.
// ---------------------------------------------------------------------------
__global__ __launch_bounds__(256) void prep_feat(const float* __restrict__ x,
                                                 uint8_t* __restrict__ A8,
                                                 __bf16* __restrict__ Ab,
                                                 float* __restrict__ C) {
    const int t  = blockIdx.x * 256 + threadIdx.x;   // over B*I/16
    const int b  = t >> 6;
    const int i0 = (t & 63) * 16;

    // zero the output accumulator (stream-ordered before gemm)
    {
        float4 z = make_float4(0.f, 0.f, 0.f, 0.f);
        float4* cz = (float4*)(C + (size_t)t * 16);
        cz[0] = z; cz[1] = z; cz[2] = z; cz[3] = z;
    }

    float xv[16];
    {
        const float4* xp = (const float4*)(x + (size_t)b * IN_DIM + i0);
        float4 q0 = xp[0], q1 = xp[1], q2 = xp[2], q3 = xp[3];
        xv[0]=q0.x;  xv[1]=q0.y;  xv[2]=q0.z;  xv[3]=q0.w;
        xv[4]=q1.x;  xv[5]=q1.y;  xv[6]=q1.z;  xv[7]=q1.w;
        xv[8]=q2.x;  xv[9]=q2.y;  xv[10]=q2.z; xv[11]=q2.w;
        xv[12]=q3.x; xv[13]=q3.y; xv[14]=q3.z; xv[15]=q3.w;
    }

    float c1[16], s1[16], ck[16], sk[16];
    bf16x8 va, vb;
#pragma unroll
    for (int j = 0; j < 16; ++j) {
        float e  = __expf(-xv[j]);
        float sl = xv[j] * __builtin_amdgcn_rcpf(1.f + e);
        if (j < 8) va[j & 7] = (__bf16)sl; else vb[j & 7] = (__bf16)sl;
        s1[j] = __sinf(xv[j]);
        c1[j] = __cosf(xv[j]);
        ck[j] = c1[j]; sk[j] = s1[j];
    }
    *(bf16x8*)(Ab + (size_t)b * IN_DIM + i0)     = va;
    *(bf16x8*)(Ab + (size_t)b * IN_DIM + i0 + 8) = vb;

    uint8_t* a8 = A8 + (size_t)b * K8 + i0;
#pragma unroll
    for (int g = 0; g < GRID_G; ++g) {
        // store plane g = angle (g+1)*x from current (ck, sk), then advance
        i32x4 wc, ws;
#pragma unroll
        for (int q = 0; q < 4; ++q) {
            int dc = 0, ds = 0;
            dc = __builtin_amdgcn_cvt_pk_fp8_f32(ck[4*q+0], ck[4*q+1], dc, false);
            dc = __builtin_amdgcn_cvt_pk_fp8_f32(ck[4*q+2], ck[4*q+3], dc, true);
            ds = __builtin_amdgcn_cvt_pk_fp8_f32(sk[4*q+0], sk[4*q+1], ds, false);
            ds = __builtin_amdgcn_cvt_pk_fp8_f32(sk[4*q+2], sk[4*q+3], ds, true);
            wc[q] = dc; ws[q] = ds;
        }
        *(i32x4*)(a8 + (size_t)g * IN_DIM)            = wc;
        *(i32x4*)(a8 + (size_t)(GRID_G + g) * IN_DIM) = ws;
        if (g < GRID_G - 1) {
#pragma unroll
            for (int j = 0; j < 16; ++j) {
                float cn = ck[j] * c1[j] - sk[j] * s1[j];
                float sn = sk[j] * c1[j] + ck[j] * s1[j];
                ck[j] = cn; sk[j] = sn;
            }
        }
    }
}

// ---------------------------------------------------------------------------
// prep_w: weight fold. 4 consecutive i per thread so the in-register
// transpose buffer is c[4][8] (32 VGPRs) instead of c[8][8] (64) — keeps the
// live set ~50 regs, far from any spill cliff.
//   W8[o, p*1024+i] = ss*coeff*WSCALE (fp8);  Wb[o,i] = scale_base (bf16).
// ---------------------------------------------------------------------------
__global__ __launch_bounds__(256) void prep_w(const float* __restrict__ sb,
                                              const float* __restrict__ ss,
                                              const float* __restrict__ coeff,
                                              uint8_t* __restrict__ W8,
                                              __bf16* __restrict__ Wb) {
    const int t  = blockIdx.x * 256 + threadIdx.x;   // over O*I/4
    const int o  = t >> 8;
    const int i0 = (t & 255) * 4;
    const size_t oi = (size_t)o * IN_DIM + i0;

    const float4 s4 = *(const float4*)(ss + oi);
    const float  s[4] = {s4.x * WSCALE, s4.y * WSCALE, s4.z * WSCALE, s4.w * WSCALE};

    {
        float4 b4 = *(const float4*)(sb + oi);
        bf16x4 w;
        w[0] = (__bf16)b4.x; w[1] = (__bf16)b4.y;
        w[2] = (__bf16)b4.z; w[3] = (__bf16)b4.w;
        *(bf16x4*)(Wb + oi) = w;
    }

    uint8_t* w8 = W8 + (size_t)o * K8 + i0;
#pragma unroll
    for (int p = 0; p < 2; ++p) {
        const float* cp = coeff + ((size_t)p * OUT_DIM * IN_DIM + oi) * GRID_G;
        float c[4][8];
#pragma unroll
        for (int j = 0; j < 4; ++j) {
            const float4* cj = (const float4*)(cp + (size_t)j * GRID_G);
            float4 a0 = cj[0], a1 = cj[1];
            c[j][0]=a0.x; c[j][1]=a0.y; c[j][2]=a0.z; c[j][3]=a0.w;
            c[j][4]=a1.x; c[j][5]=a1.y; c[j][6]=a1.z; c[j][7]=a1.w;
        }
#pragma unroll
        for (int g = 0; g < GRID_G; ++g) {
            int d = 0;
            d = __builtin_amdgcn_cvt_pk_fp8_f32(s[0]*c[0][g], s[1]*c[1][g], d, false);
            d = __builtin_amdgcn_cvt_pk_fp8_f32(s[2]*c[2][g], s[3]*c[3][g], d, true);
            *(int*)(w8 + (size_t)(p * GRID_G + g) * IN_DIM) = d;
        }
    }
}

// ---------------------------------------------------------------------------
// Unified GEMM. Grid (8, 32, 5):
//   z in [0,4): spline fp8, MX-scaled mfma 16x16x128 (unit scales), split-K x4,
//               BK=128 bytes, 32 iters/block.
//   z == 4:     base bf16, mfma 16x16x32, full K=1024, 16 iters of 64 elems.
// Both: 128x128 tile, 4 waves 2x2, 32 KB LDS, XOR 16B-chunk swizzle
// (c ^ (row&7)) on staging global addr -> conflict-free b128 frag reads.
// NEW: XCD-aware (bm,bn) swizzle — MI355X round-robins linear block id over
// 8 XCDs; map so each XCD owns an 8bm x 4bn sub-grid, making A/B panels
// L2-local instead of being refetched by all 8 XCDs.
// Epilogue: HW f32 atomic add into zeroed C (proven under graph capture).
// ---------------------------------------------------------------------------
__global__ __launch_bounds__(256, 4) void gemm_all(const uint8_t* __restrict__ A8,
                                                   const uint8_t* __restrict__ W8,
                                                   const uint8_t* __restrict__ Ab,
                                                   const uint8_t* __restrict__ Wb,
                                                   float* __restrict__ C) {
    __shared__ __align__(16) uint8_t As[16384];
    __shared__ __align__(16) uint8_t Bs[16384];
    const int tid = threadIdx.x;
    const int w   = tid >> 6;
    const int l   = tid & 63;
    // XCD swizzle: flat 0..255, xcd = flat&7 (dispatch round-robin model)
    const int flat = blockIdx.y * 8 + blockIdx.x;
    const int xcd  = flat & 7;
    const int idx  = flat >> 3;                 // 0..31 within XCD
    const int bn   = (xcd & 1) * 4 + (idx & 3); // N/128 = 8
    const int bm   = (xcd >> 1) * 8 + (idx >> 2); // M/128 = 32
    const int kz  = blockIdx.z;    // 0..3 spline chunks, 4 = base
    const int wm  = w & 1;
    const int wn  = w >> 1;

    f32x4 acc[4][4] = {};

    const int srow   = l >> 3;                  // 0..7
    const int schunk = ((l & 7) ^ srow) * 16;   // byte offset of swizzled 16B chunk
    const int lm = l & 15;
    const int q  = l >> 4;                      // 0..3
    float oscale;

    if (kz < SPLIT8) {
        // ---------------- spline fp8 path ----------------
        const uint8_t* Ag = A8 + (size_t)(bm * 128 + w * 32 + srow) * K8 + kz * (K8 / SPLIT8) + schunk;
        const uint8_t* Bg = W8 + (size_t)(bn * 128 + w * 32 + srow) * K8 + kz * (K8 / SPLIT8) + schunk;
        const int c0 = (q * 2) << 4, c1 = (q * 2 + 1) << 4;   // lane's two chunk offsets

        for (int ks = 0; ks < (K8 / SPLIT8) / 128; ++ks) {
#pragma unroll
            for (int j = 0; j < 4; ++j) {
                __builtin_amdgcn_global_load_lds(
                    (const uint32_t*)(Ag + (size_t)(j * 8) * K8),
                    (uint32_t*)(As + (w * 32 + j * 8) * 128), 16, 0, 0);
                __builtin_amdgcn_global_load_lds(
                    (const uint32_t*)(Bg + (size_t)(j * 8) * K8),
                    (uint32_t*)(Bs + (w * 32 + j * 8) * 128), 16, 0, 0);
            }
            Ag += 128; Bg += 128;
            __syncthreads();

            i32x8 bf[4];
#pragma unroll
            for (int j = 0; j < 4; ++j) {
                const int row = wn * 64 + j * 16 + lm;
                const int sw  = (row & 7) << 4;
                const uint8_t* rp = Bs + row * 128;
                i32x4 lo = *(const i32x4*)(rp + (c0 ^ sw));
                i32x4 hi = *(const i32x4*)(rp + (c1 ^ sw));
                bf[j] = __builtin_shufflevector(lo, hi, 0, 1, 2, 3, 4, 5, 6, 7);
            }
#pragma unroll
            for (int i = 0; i < 4; ++i) {
                const int row = wm * 64 + i * 16 + lm;
                const int sw  = (row & 7) << 4;
                const uint8_t* rp = As + row * 128;
                i32x4 lo = *(const i32x4*)(rp + (c0 ^ sw));
                i32x4 hi = *(const i32x4*)(rp + (c1 ^ sw));
                i32x8 af = __builtin_shufflevector(lo, hi, 0, 1, 2, 3, 4, 5, 6, 7);
#pragma unroll
                for (int j = 0; j < 4; ++j)
                    acc[i][j] = __builtin_amdgcn_mfma_scale_f32_16x16x128_f8f6f4(
                        af, bf[j], acc[i][j], 0, 0, 0, 0x7f7f7f7f, 0, 0x7f7f7f7f);
            }
            __syncthreads();
        }
        oscale = 1.0f / WSCALE;
    } else {
        // ---------------- base bf16 path (full K, no split) ----------------
        const uint8_t* Ag = Ab + (size_t)(bm * 128 + w * 32 + srow) * (KB * 2) + schunk;
        const uint8_t* Bg = Wb + (size_t)(bn * 128 + w * 32 + srow) * (KB * 2) + schunk;

        for (int ks = 0; ks < (KB * 2) / 128; ++ks) {
#pragma unroll
            for (int j = 0; j < 4; ++j) {
                __builtin_amdgcn_global_load_lds(
                    (const uint32_t*)(Ag + (size_t)(j * 8) * (KB * 2)),
                    (uint32_t*)(As + (w * 32 + j * 8) * 128), 16, 0, 0);
                __builtin_amdgcn_global_load_lds(
                    (const uint32_t*)(Bg + (size_t)(j * 8) * (KB * 2)),
                    (uint32_t*)(Bs + (w * 32 + j * 8) * 128), 16, 0, 0);
            }
            Ag += 128; Bg += 128;
            __syncthreads();

#pragma unroll
            for (int h = 0; h < 2; ++h) {
                bf16x8 af[4], bfr[4];
#pragma unroll
                for (int i = 0; i < 4; ++i) {
                    const int row = wm * 64 + i * 16 + lm;
                    af[i] = *(const bf16x8*)(As + row * 128 + ((((h * 4 + q) ^ (row & 7))) << 4));
                }
#pragma unroll
                for (int j = 0; j < 4; ++j) {
                    const int row = wn * 64 + j * 16 + lm;
                    bfr[j] = *(const bf16x8*)(Bs + row * 128 + ((((h * 4 + q) ^ (row & 7))) << 4));
                }
#pragma unroll
                for (int i = 0; i < 4; ++i)
#pragma unroll
                    for (int j = 0; j < 4; ++j)
                        acc[i][j] = __builtin_amdgcn_mfma_f32_16x16x32_bf16(af[i], bfr[j], acc[i][j], 0, 0, 0);
            }
            __syncthreads();
        }
        oscale = 1.0f;
    }

    // epilogue: C/D layout col = lane&15, row = (lane>>4)*4 + reg
    const int row0 = bm * 128 + wm * 64 + q * 4;
    const int col0 = bn * 128 + wn * 64 + lm;
#pragma unroll
    for (int i = 0; i < 4; ++i)
#pragma unroll
        for (int j = 0; j < 4; ++j)
#pragma unroll
            for (int r = 0; r < 4; ++r)
                unsafeAtomicAdd(&C[(size_t)(row0 + i * 16 + r) * OUT_DIM + col0 + j * 16],
                                acc[i][j][r] * oscale);
}

// ---------------------------------------------------------------------------
extern "C" void kernel_launch(void* const* d_in, const int* in_sizes, int n_in,
                              void* d_out, int out_size, void* d_ws, size_t ws_size,
                              hipStream_t stream) {
    const float* x     = (const float*)d_in[0];   // (B, I)
    const float* sb    = (const float*)d_in[1];   // (O, I)
    const float* ss    = (const float*)d_in[2];   // (O, I)
    const float* coeff = (const float*)d_in[3];   // (2, O, I, G)
    float* out = (float*)d_out;                   // (B, O)

    uint8_t* A8 = (uint8_t*)d_ws;                          // 4096*16384 fp8 = 67.1 MB
    uint8_t* W8 = A8 + (size_t)BATCH * K8;                 // 1024*16384 fp8 = 16.8 MB
    __bf16*  Ab = (__bf16*)(W8 + (size_t)OUT_DIM * K8);    // 4096*1024 bf16 = 8.4 MB
    __bf16*  Wb = Ab + (size_t)BATCH * KB;                 // 1024*1024 bf16 = 2.1 MB

    hipLaunchKernelGGL(prep_feat, dim3(BATCH * IN_DIM / 16 / 256), dim3(256), 0, stream,
                       x, A8, Ab, out);
    hipLaunchKernelGGL(prep_w, dim3(OUT_DIM * IN_DIM / 4 / 256), dim3(256), 0, stream,
                       sb, ss, coeff, W8, Wb);
    hipLaunchKernelGGL(gemm_all, dim3(OUT_DIM / 128, BATCH / 128, SPLIT8 + 1), dim3(256), 0, stream,
                       A8, W8, (const uint8_t*)Ab, (const uint8_t*)Wb, out);
}

// Round 2
// 246.991 us; speedup vs baseline: 1.1206x; 1.0328x over previous
//
#include <hip/hip_runtime.h>
#include <hip/hip_bf16.h>
#include <stdint.h>

#define BATCH   4096
#define IN_DIM  1024
#define OUT_DIM 1024
#define GRID_G  8
#define K8      16384            // spline K: 16 planes (8 cos + 8 sin) * 1024
#define KB      1024             // base K (silu plane)
#define SPLIT8  4                // spline split-K: 4 chunks of 32 iters (BK=128 B)
#define WSCALE  256.0f           // spline weights scaled into e4m3 range

typedef __bf16 bf16x8 __attribute__((ext_vector_type(8)));
typedef __bf16 bf16x4 __attribute__((ext_vector_type(4)));
typedef float  f32x4  __attribute__((ext_vector_type(4)));
typedef int    i32x4  __attribute__((ext_vector_type(4)));
typedef int    i32x8  __attribute__((ext_vector_type(8)));

// ---------------------------------------------------------------------------
// prep_feat: features for A. 16 consecutive i per thread.  (unchanged r1->r2)
//   - silu(x) -> Ab (bf16)
//   - cos(g x), sin(g x) g=1..8 -> A8 fp8 planes [b, p*1024+i] (p<8 cos, p>=8 sin)
//   - also zeroes C (64 B/thread == exactly B*O floats)
// ---------------------------------------------------------------------------
__global__ __launch_bounds__(256) void prep_feat(const float* __restrict__ x,
                                                 uint8_t* __restrict__ A8,
                                                 __bf16* __restrict__ Ab,
                                                 float* __restrict__ C) {
    const int t  = blockIdx.x * 256 + threadIdx.x;   // over B*I/16
    const int b  = t >> 6;
    const int i0 = (t & 63) * 16;

    // zero the output accumulator (stream-ordered before gemm)
    {
        float4 z = make_float4(0.f, 0.f, 0.f, 0.f);
        float4* cz = (float4*)(C + (size_t)t * 16);
        cz[0] = z; cz[1] = z; cz[2] = z; cz[3] = z;
    }

    float xv[16];
    {
        const float4* xp = (const float4*)(x + (size_t)b * IN_DIM + i0);
        float4 q0 = xp[0], q1 = xp[1], q2 = xp[2], q3 = xp[3];
        xv[0]=q0.x;  xv[1]=q0.y;  xv[2]=q0.z;  xv[3]=q0.w;
        xv[4]=q1.x;  xv[5]=q1.y;  xv[6]=q1.z;  xv[7]=q1.w;
        xv[8]=q2.x;  xv[9]=q2.y;  xv[10]=q2.z; xv[11]=q2.w;
        xv[12]=q3.x; xv[13]=q3.y; xv[14]=q3.z; xv[15]=q3.w;
    }

    float c1[16], s1[16], ck[16], sk[16];
    bf16x8 va, vb;
#pragma unroll
    for (int j = 0; j < 16; ++j) {
        float e  = __expf(-xv[j]);
        float sl = xv[j] * __builtin_amdgcn_rcpf(1.f + e);
        if (j < 8) va[j & 7] = (__bf16)sl; else vb[j & 7] = (__bf16)sl;
        s1[j] = __sinf(xv[j]);
        c1[j] = __cosf(xv[j]);
        ck[j] = c1[j]; sk[j] = s1[j];
    }
    *(bf16x8*)(Ab + (size_t)b * IN_DIM + i0)     = va;
    *(bf16x8*)(Ab + (size_t)b * IN_DIM + i0 + 8) = vb;

    uint8_t* a8 = A8 + (size_t)b * K8 + i0;
#pragma unroll
    for (int g = 0; g < GRID_G; ++g) {
        i32x4 wc, ws;
#pragma unroll
        for (int q = 0; q < 4; ++q) {
            int dc = 0, ds = 0;
            dc = __builtin_amdgcn_cvt_pk_fp8_f32(ck[4*q+0], ck[4*q+1], dc, false);
            dc = __builtin_amdgcn_cvt_pk_fp8_f32(ck[4*q+2], ck[4*q+3], dc, true);
            ds = __builtin_amdgcn_cvt_pk_fp8_f32(sk[4*q+0], sk[4*q+1], ds, false);
            ds = __builtin_amdgcn_cvt_pk_fp8_f32(sk[4*q+2], sk[4*q+3], ds, true);
            wc[q] = dc; ws[q] = ds;
        }
        *(i32x4*)(a8 + (size_t)g * IN_DIM)            = wc;
        *(i32x4*)(a8 + (size_t)(GRID_G + g) * IN_DIM) = ws;
        if (g < GRID_G - 1) {
#pragma unroll
            for (int j = 0; j < 16; ++j) {
                float cn = ck[j] * c1[j] - sk[j] * s1[j];
                float sn = sk[j] * c1[j] + ck[j] * s1[j];
                ck[j] = cn; sk[j] = sn;
            }
        }
    }
}

// ---------------------------------------------------------------------------
// prep_w: weight fold. 4 consecutive i per thread.  (unchanged r1->r2)
//   W8[o, p*1024+i] = ss*coeff*WSCALE (fp8);  Wb[o,i] = scale_base (bf16).
// ---------------------------------------------------------------------------
__global__ __launch_bounds__(256) void prep_w(const float* __restrict__ sb,
                                              const float* __restrict__ ss,
                                              const float* __restrict__ coeff,
                                              uint8_t* __restrict__ W8,
                                              __bf16* __restrict__ Wb) {
    const int t  = blockIdx.x * 256 + threadIdx.x;   // over O*I/4
    const int o  = t >> 8;
    const int i0 = (t & 255) * 4;
    const size_t oi = (size_t)o * IN_DIM + i0;

    const float4 s4 = *(const float4*)(ss + oi);
    const float  s[4] = {s4.x * WSCALE, s4.y * WSCALE, s4.z * WSCALE, s4.w * WSCALE};

    {
        float4 b4 = *(const float4*)(sb + oi);
        bf16x4 w;
        w[0] = (__bf16)b4.x; w[1] = (__bf16)b4.y;
        w[2] = (__bf16)b4.z; w[3] = (__bf16)b4.w;
        *(bf16x4*)(Wb + oi) = w;
    }

    uint8_t* w8 = W8 + (size_t)o * K8 + i0;
#pragma unroll
    for (int p = 0; p < 2; ++p) {
        const float* cp = coeff + ((size_t)p * OUT_DIM * IN_DIM + oi) * GRID_G;
        float c[4][8];
#pragma unroll
        for (int j = 0; j < 4; ++j) {
            const float4* cj = (const float4*)(cp + (size_t)j * GRID_G);
            float4 a0 = cj[0], a1 = cj[1];
            c[j][0]=a0.x; c[j][1]=a0.y; c[j][2]=a0.z; c[j][3]=a0.w;
            c[j][4]=a1.x; c[j][5]=a1.y; c[j][6]=a1.z; c[j][7]=a1.w;
        }
#pragma unroll
        for (int g = 0; g < GRID_G; ++g) {
            int d = 0;
            d = __builtin_amdgcn_cvt_pk_fp8_f32(s[0]*c[0][g], s[1]*c[1][g], d, false);
            d = __builtin_amdgcn_cvt_pk_fp8_f32(s[2]*c[2][g], s[3]*c[3][g], d, true);
            *(int*)(w8 + (size_t)(p * GRID_G + g) * IN_DIM) = d;
        }
    }
}

// ---------------------------------------------------------------------------
// Unified GEMM. Grid (8, 32, 4) = 1024 blocks = EXACTLY 4 blocks/CU resident
// (was (8,32,5)=1280 -> 1024 + a 256-block drain round at 1/4 occupancy).
//   z in [0,4): spline fp8 chunk kz (4 planes, 32 iters of BK=128 B),
//               MX-scaled mfma 16x16x128 (unit scales).
//   z == 0 additionally runs the base bf16 GEMM (full K=1024, 16 iters)
//          accumulating into the SAME acc after an in-register 1/WSCALE
//          rescale -> one fewer atomic C-pass (84->67 MB) and no 5th round.
// Dispatch is z-major, so each CU gets one block of each kz:
// per-CU work = 48+32+32+32 = 144 iters, perfectly balanced, zero tail.
// 128x128 tile, 4 waves 2x2, 32 KB LDS, XOR 16B-chunk swizzle (c ^ (row&7))
// on staging global addr -> conflict-free b128 frag reads. XCD-aware (bm,bn)
// swizzle (each XCD owns an 8bm x 4bn sub-grid; FETCH 308->120 MB in r1).
// Epilogue: HW f32 atomic add into zeroed C (proven under graph capture).
// ---------------------------------------------------------------------------
__global__ __launch_bounds__(256, 4) void gemm_all(const uint8_t* __restrict__ A8,
                                                   const uint8_t* __restrict__ W8,
                                                   const uint8_t* __restrict__ Ab,
                                                   const uint8_t* __restrict__ Wb,
                                                   float* __restrict__ C) {
    __shared__ __align__(16) uint8_t As[16384];
    __shared__ __align__(16) uint8_t Bs[16384];
    const int tid = threadIdx.x;
    const int w   = tid >> 6;
    const int l   = tid & 63;
    // XCD swizzle: flat 0..255, xcd = flat&7 (dispatch round-robin model)
    const int flat = blockIdx.y * 8 + blockIdx.x;
    const int xcd  = flat & 7;
    const int idx  = flat >> 3;                   // 0..31 within XCD
    const int bn   = (xcd & 1) * 4 + (idx & 3);   // N/128 = 8
    const int bm   = (xcd >> 1) * 8 + (idx >> 2); // M/128 = 32
    const int kz  = blockIdx.z;                   // 0..3 spline chunks
    const int wm  = w & 1;
    const int wn  = w >> 1;

    f32x4 acc[4][4] = {};

    const int srow   = l >> 3;                  // 0..7
    const int schunk = ((l & 7) ^ srow) * 16;   // byte offset of swizzled 16B chunk
    const int lm = l & 15;
    const int q  = l >> 4;                      // 0..3

    // ---------------- spline fp8 phase (all blocks) ----------------
    {
        const uint8_t* Ag = A8 + (size_t)(bm * 128 + w * 32 + srow) * K8 + kz * (K8 / SPLIT8) + schunk;
        const uint8_t* Bg = W8 + (size_t)(bn * 128 + w * 32 + srow) * K8 + kz * (K8 / SPLIT8) + schunk;
        const int c0 = (q * 2) << 4, c1 = (q * 2 + 1) << 4;   // lane's two chunk offsets

        for (int ks = 0; ks < (K8 / SPLIT8) / 128; ++ks) {
#pragma unroll
            for (int j = 0; j < 4; ++j) {
                __builtin_amdgcn_global_load_lds(
                    (const uint32_t*)(Ag + (size_t)(j * 8) * K8),
                    (uint32_t*)(As + (w * 32 + j * 8) * 128), 16, 0, 0);
                __builtin_amdgcn_global_load_lds(
                    (const uint32_t*)(Bg + (size_t)(j * 8) * K8),
                    (uint32_t*)(Bs + (w * 32 + j * 8) * 128), 16, 0, 0);
            }
            Ag += 128; Bg += 128;
            __syncthreads();

            i32x8 bf[4];
#pragma unroll
            for (int j = 0; j < 4; ++j) {
                const int row = wn * 64 + j * 16 + lm;
                const int sw  = (row & 7) << 4;
                const uint8_t* rp = Bs + row * 128;
                i32x4 lo = *(const i32x4*)(rp + (c0 ^ sw));
                i32x4 hi = *(const i32x4*)(rp + (c1 ^ sw));
                bf[j] = __builtin_shufflevector(lo, hi, 0, 1, 2, 3, 4, 5, 6, 7);
            }
#pragma unroll
            for (int i = 0; i < 4; ++i) {
                const int row = wm * 64 + i * 16 + lm;
                const int sw  = (row & 7) << 4;
                const uint8_t* rp = As + row * 128;
                i32x4 lo = *(const i32x4*)(rp + (c0 ^ sw));
                i32x4 hi = *(const i32x4*)(rp + (c1 ^ sw));
                i32x8 af = __builtin_shufflevector(lo, hi, 0, 1, 2, 3, 4, 5, 6, 7);
#pragma unroll
                for (int j = 0; j < 4; ++j)
                    acc[i][j] = __builtin_amdgcn_mfma_scale_f32_16x16x128_f8f6f4(
                        af, bf[j], acc[i][j], 0, 0, 0, 0x7f7f7f7f, 0, 0x7f7f7f7f);
            }
            __syncthreads();
        }
    }

    // undo the WSCALE applied to the fp8 spline weights (in-register)
#pragma unroll
    for (int i = 0; i < 4; ++i)
#pragma unroll
        for (int j = 0; j < 4; ++j)
            acc[i][j] *= (1.0f / WSCALE);

    // ---------------- base bf16 phase (kz==0 blocks only) ----------------
    if (kz == 0) {
        const uint8_t* Ag = Ab + (size_t)(bm * 128 + w * 32 + srow) * (KB * 2) + schunk;
        const uint8_t* Bg = Wb + (size_t)(bn * 128 + w * 32 + srow) * (KB * 2) + schunk;

        for (int ks = 0; ks < (KB * 2) / 128; ++ks) {
#pragma unroll
            for (int j = 0; j < 4; ++j) {
                __builtin_amdgcn_global_load_lds(
                    (const uint32_t*)(Ag + (size_t)(j * 8) * (KB * 2)),
                    (uint32_t*)(As + (w * 32 + j * 8) * 128), 16, 0, 0);
                __builtin_amdgcn_global_load_lds(
                    (const uint32_t*)(Bg + (size_t)(j * 8) * (KB * 2)),
                    (uint32_t*)(Bs + (w * 32 + j * 8) * 128), 16, 0, 0);
            }
            Ag += 128; Bg += 128;
            __syncthreads();

#pragma unroll
            for (int h = 0; h < 2; ++h) {
                bf16x8 af[4], bfr[4];
#pragma unroll
                for (int i = 0; i < 4; ++i) {
                    const int row = wm * 64 + i * 16 + lm;
                    af[i] = *(const bf16x8*)(As + row * 128 + ((((h * 4 + q) ^ (row & 7))) << 4));
                }
#pragma unroll
                for (int j = 0; j < 4; ++j) {
                    const int row = wn * 64 + j * 16 + lm;
                    bfr[j] = *(const bf16x8*)(Bs + row * 128 + ((((h * 4 + q) ^ (row & 7))) << 4));
                }
#pragma unroll
                for (int i = 0; i < 4; ++i)
#pragma unroll
                    for (int j = 0; j < 4; ++j)
                        acc[i][j] = __builtin_amdgcn_mfma_f32_16x16x32_bf16(af[i], bfr[j], acc[i][j], 0, 0, 0);
            }
            __syncthreads();
        }
    }

    // epilogue: C/D layout col = lane&15, row = (lane>>4)*4 + reg
    const int row0 = bm * 128 + wm * 64 + q * 4;
    const int col0 = bn * 128 + wn * 64 + lm;
#pragma unroll
    for (int i = 0; i < 4; ++i)
#pragma unroll
        for (int j = 0; j < 4; ++j)
#pragma unroll
            for (int r = 0; r < 4; ++r)
                unsafeAtomicAdd(&C[(size_t)(row0 + i * 16 + r) * OUT_DIM + col0 + j * 16],
                                acc[i][j][r]);
}

// ---------------------------------------------------------------------------
extern "C" void kernel_launch(void* const* d_in, const int* in_sizes, int n_in,
                              void* d_out, int out_size, void* d_ws, size_t ws_size,
                              hipStream_t stream) {
    const float* x     = (const float*)d_in[0];   // (B, I)
    const float* sb    = (const float*)d_in[1];   // (O, I)
    const float* ss    = (const float*)d_in[2];   // (O, I)
    const float* coeff = (const float*)d_in[3];   // (2, O, I, G)
    float* out = (float*)d_out;                   // (B, O)

    uint8_t* A8 = (uint8_t*)d_ws;                          // 4096*16384 fp8 = 67.1 MB
    uint8_t* W8 = A8 + (size_t)BATCH * K8;                 // 1024*16384 fp8 = 16.8 MB
    __bf16*  Ab = (__bf16*)(W8 + (size_t)OUT_DIM * K8);    // 4096*1024 bf16 = 8.4 MB
    __bf16*  Wb = Ab + (size_t)BATCH * KB;                 // 1024*1024 bf16 = 2.1 MB

    hipLaunchKernelGGL(prep_feat, dim3(BATCH * IN_DIM / 16 / 256), dim3(256), 0, stream,
                       x, A8, Ab, out);
    hipLaunchKernelGGL(prep_w, dim3(OUT_DIM * IN_DIM / 4 / 256), dim3(256), 0, stream,
                       sb, ss, coeff, W8, Wb);
    hipLaunchKernelGGL(gemm_all, dim3(OUT_DIM / 128, BATCH / 128, SPLIT8), dim3(256), 0, stream,
                       A8, W8, (const uint8_t*)Ab, (const uint8_t*)Wb, out);
}

// Round 3
// 238.360 us; speedup vs baseline: 1.1612x; 1.0362x over previous
//
#include <hip/hip_runtime.h>
#include <hip/hip_bf16.h>
#include <stdint.h>

#define BATCH   4096
#define IN_DIM  1024
#define OUT_DIM 1024
#define GRID_G  8
#define K8      16384            // spline K: 16 planes (8 cos + 8 sin) * 1024
#define KB      1024             // base K (silu plane)
#define SPLIT8  4                // spline split-K: 4 chunks of 32 iters (BK=128 B)
#define WSCALE  256.0f           // spline weights scaled into e4m3 range

typedef __bf16 bf16x8 __attribute__((ext_vector_type(8)));
typedef __bf16 bf16x4 __attribute__((ext_vector_type(4)));
typedef float  f32x4  __attribute__((ext_vector_type(4)));
typedef int    i32x4  __attribute__((ext_vector_type(4)));
typedef int    i32x8  __attribute__((ext_vector_type(8)));

// ---------------------------------------------------------------------------
// prep_feat: features for A. 16 consecutive i per thread.
//   - silu(x) -> Ab (bf16)
//   - cos(g x), sin(g x) g=1..8 -> A8 fp8 planes [b, p*1024+i] (p<8 cos, p>=8 sin)
//   - also zeroes C. r2->r3: C-zero is now wave-contiguous (inst j covers a
//     contiguous 4 KB across the wave) instead of per-lane stride-64.
// ---------------------------------------------------------------------------
__global__ __launch_bounds__(256) void prep_feat(const float* __restrict__ x,
                                                 uint8_t* __restrict__ A8,
                                                 __bf16* __restrict__ Ab,
                                                 float* __restrict__ C) {
    const int t  = blockIdx.x * 256 + threadIdx.x;   // over B*I/16
    const int b  = t >> 6;
    const int i0 = (t & 63) * 16;

    // zero the output accumulator (stream-ordered before gemm), coalesced:
    // block zeroes a contiguous 16 KB region of C.
    {
        float4 z = make_float4(0.f, 0.f, 0.f, 0.f);
        float4* cz = (float4*)(C + (size_t)blockIdx.x * 4096);
#pragma unroll
        for (int j = 0; j < 4; ++j) cz[j * 256 + threadIdx.x] = z;
    }

    float xv[16];
    {
        const float4* xp = (const float4*)(x + (size_t)b * IN_DIM + i0);
        float4 q0 = xp[0], q1 = xp[1], q2 = xp[2], q3 = xp[3];
        xv[0]=q0.x;  xv[1]=q0.y;  xv[2]=q0.z;  xv[3]=q0.w;
        xv[4]=q1.x;  xv[5]=q1.y;  xv[6]=q1.z;  xv[7]=q1.w;
        xv[8]=q2.x;  xv[9]=q2.y;  xv[10]=q2.z; xv[11]=q2.w;
        xv[12]=q3.x; xv[13]=q3.y; xv[14]=q3.z; xv[15]=q3.w;
    }

    float c1[16], s1[16], ck[16], sk[16];
    bf16x8 va, vb;
#pragma unroll
    for (int j = 0; j < 16; ++j) {
        float e  = __expf(-xv[j]);
        float sl = xv[j] * __builtin_amdgcn_rcpf(1.f + e);
        if (j < 8) va[j & 7] = (__bf16)sl; else vb[j & 7] = (__bf16)sl;
        s1[j] = __sinf(xv[j]);
        c1[j] = __cosf(xv[j]);
        ck[j] = c1[j]; sk[j] = s1[j];
    }
    *(bf16x8*)(Ab + (size_t)b * IN_DIM + i0)     = va;
    *(bf16x8*)(Ab + (size_t)b * IN_DIM + i0 + 8) = vb;

    uint8_t* a8 = A8 + (size_t)b * K8 + i0;
#pragma unroll
    for (int g = 0; g < GRID_G; ++g) {
        i32x4 wc, ws;
#pragma unroll
        for (int q = 0; q < 4; ++q) {
            int dc = 0, ds = 0;
            dc = __builtin_amdgcn_cvt_pk_fp8_f32(ck[4*q+0], ck[4*q+1], dc, false);
            dc = __builtin_amdgcn_cvt_pk_fp8_f32(ck[4*q+2], ck[4*q+3], dc, true);
            ds = __builtin_amdgcn_cvt_pk_fp8_f32(sk[4*q+0], sk[4*q+1], ds, false);
            ds = __builtin_amdgcn_cvt_pk_fp8_f32(sk[4*q+2], sk[4*q+3], ds, true);
            wc[q] = dc; ws[q] = ds;
        }
        *(i32x4*)(a8 + (size_t)g * IN_DIM)            = wc;
        *(i32x4*)(a8 + (size_t)(GRID_G + g) * IN_DIM) = ws;
        if (g < GRID_G - 1) {
#pragma unroll
            for (int j = 0; j < 16; ++j) {
                float cn = ck[j] * c1[j] - sk[j] * s1[j];
                float sn = sk[j] * c1[j] + ck[j] * s1[j];
                ck[j] = cn; sk[j] = sn;
            }
        }
    }
}

// ---------------------------------------------------------------------------
// prep_w: weight fold, one o-row per block.
//   W8[o, p*1024+i] = ss*coeff*WSCALE (fp8);  Wb[o,i] = scale_base (bf16).
// r2->r3: coeff (67 MB, the big input) was read with per-lane-contiguous
// 128 B blocks -> every dwordx4 issued at lane-stride 128 B (16/64 B used
// per line per inst). Now: stage the (p,o) 32 KB slab through LDS with 8
// perfectly-coalesced dwordx4 (4 KB contiguous per inst), XOR 16B-chunk
// swizzle (ch ^ (row&7)) so the per-thread 128 B read-back hits the b128
// bank floor instead of a 32-way conflict. Identical floats -> bit-identical
// fp8 output.
// ---------------------------------------------------------------------------
__global__ __launch_bounds__(256) void prep_w(const float* __restrict__ sb,
                                              const float* __restrict__ ss,
                                              const float* __restrict__ coeff,
                                              uint8_t* __restrict__ W8,
                                              __bf16* __restrict__ Wb) {
    __shared__ __align__(16) float lds[8192];        // 32 KB
    const int tid = threadIdx.x;
    const int o   = blockIdx.x;                      // one output row per block
    const int i0  = tid * 4;
    const size_t oi = (size_t)o * IN_DIM + i0;

    const float4 s4 = *(const float4*)(ss + oi);     // lane-stride 16 B: coalesced
    const float  s[4] = {s4.x * WSCALE, s4.y * WSCALE, s4.z * WSCALE, s4.w * WSCALE};

    {
        float4 b4 = *(const float4*)(sb + oi);
        bf16x4 wv;
        wv[0] = (__bf16)b4.x; wv[1] = (__bf16)b4.y;
        wv[2] = (__bf16)b4.z; wv[3] = (__bf16)b4.w;
        *(bf16x4*)(Wb + oi) = wv;
    }

    uint8_t* w8 = W8 + (size_t)o * K8 + i0;
    for (int p = 0; p < 2; ++p) {
        if (p) __syncthreads();                      // protect lds reuse
        // --- coalesced stage: coeff[p][o][0..1024)[0..8) = 32 KB ---
        const float4* src = (const float4*)(coeff + ((size_t)p * OUT_DIM + o) * (IN_DIM * GRID_G));
#pragma unroll
        for (int j = 0; j < 8; ++j) {
            float4 v = src[j * 256 + tid];           // linear byte L = j*4096 + tid*16
            const int L   = j * 4096 + tid * 16;
            const int row = L >> 7;                  // 128-B row
            const int ch  = (L >> 4) & 7;            // 16-B chunk in row
            *(float4*)((uint8_t*)lds + row * 128 + ((ch ^ (row & 7)) << 4)) = v;
        }
        __syncthreads();
        // --- read back: thread's 4 elements x 8 g = 128 B = "row tid" ---
        float c[4][8];
        {
            const uint8_t* rp = (const uint8_t*)lds + tid * 128;
            const int r7 = (tid & 7) << 4;
#pragma unroll
            for (int j = 0; j < 8; ++j) {
                float4 v = *(const float4*)(rp + ((j << 4) ^ r7));
                // bytes tid*128 + j*16 = floats tid*32 + j*4
                //   -> element j>>1, g = (j&1)*4 + 0..3
                c[j >> 1][(j & 1) * 4 + 0] = v.x;
                c[j >> 1][(j & 1) * 4 + 1] = v.y;
                c[j >> 1][(j & 1) * 4 + 2] = v.z;
                c[j >> 1][(j & 1) * 4 + 3] = v.w;
            }
        }
#pragma unroll
        for (int g = 0; g < GRID_G; ++g) {
            int d = 0;
            d = __builtin_amdgcn_cvt_pk_fp8_f32(s[0]*c[0][g], s[1]*c[1][g], d, false);
            d = __builtin_amdgcn_cvt_pk_fp8_f32(s[2]*c[2][g], s[3]*c[3][g], d, true);
            *(int*)(w8 + (size_t)(p * GRID_G + g) * IN_DIM) = d;
        }
    }
}

// ---------------------------------------------------------------------------
// Unified GEMM (unchanged r2->r3). Grid (8, 32, 4) = 1024 blocks = exactly
// 4 blocks/CU resident.
//   z in [0,4): spline fp8 chunk kz (4 planes, 32 iters of BK=128 B),
//               MX-scaled mfma 16x16x128 (unit scales).
//   z == 0 additionally runs the base bf16 GEMM (full K=1024, 16 iters)
//          accumulating into the SAME acc after an in-register 1/WSCALE
//          rescale.
// 128x128 tile, 4 waves 2x2, 32 KB LDS, XOR 16B-chunk swizzle (c ^ (row&7))
// on staging global addr -> conflict-free b128 frag reads. XCD-aware (bm,bn)
// swizzle (each XCD owns an 8bm x 4bn sub-grid; FETCH 308->120 MB).
// Epilogue: HW f32 atomic add into zeroed C (proven under graph capture).
// ---------------------------------------------------------------------------
__global__ __launch_bounds__(256, 4) void gemm_all(const uint8_t* __restrict__ A8,
                                                   const uint8_t* __restrict__ W8,
                                                   const uint8_t* __restrict__ Ab,
                                                   const uint8_t* __restrict__ Wb,
                                                   float* __restrict__ C) {
    __shared__ __align__(16) uint8_t As[16384];
    __shared__ __align__(16) uint8_t Bs[16384];
    const int tid = threadIdx.x;
    const int w   = tid >> 6;
    const int l   = tid & 63;
    // XCD swizzle: flat 0..255, xcd = flat&7 (dispatch round-robin model)
    const int flat = blockIdx.y * 8 + blockIdx.x;
    const int xcd  = flat & 7;
    const int idx  = flat >> 3;                   // 0..31 within XCD
    const int bn   = (xcd & 1) * 4 + (idx & 3);   // N/128 = 8
    const int bm   = (xcd >> 1) * 8 + (idx >> 2); // M/128 = 32
    const int kz  = blockIdx.z;                   // 0..3 spline chunks
    const int wm  = w & 1;
    const int wn  = w >> 1;

    f32x4 acc[4][4] = {};

    const int srow   = l >> 3;                  // 0..7
    const int schunk = ((l & 7) ^ srow) * 16;   // byte offset of swizzled 16B chunk
    const int lm = l & 15;
    const int q  = l >> 4;                      // 0..3

    // ---------------- spline fp8 phase (all blocks) ----------------
    {
        const uint8_t* Ag = A8 + (size_t)(bm * 128 + w * 32 + srow) * K8 + kz * (K8 / SPLIT8) + schunk;
        const uint8_t* Bg = W8 + (size_t)(bn * 128 + w * 32 + srow) * K8 + kz * (K8 / SPLIT8) + schunk;
        const int c0 = (q * 2) << 4, c1 = (q * 2 + 1) << 4;   // lane's two chunk offsets

        for (int ks = 0; ks < (K8 / SPLIT8) / 128; ++ks) {
#pragma unroll
            for (int j = 0; j < 4; ++j) {
                __builtin_amdgcn_global_load_lds(
                    (const uint32_t*)(Ag + (size_t)(j * 8) * K8),
                    (uint32_t*)(As + (w * 32 + j * 8) * 128), 16, 0, 0);
                __builtin_amdgcn_global_load_lds(
                    (const uint32_t*)(Bg + (size_t)(j * 8) * K8),
                    (uint32_t*)(Bs + (w * 32 + j * 8) * 128), 16, 0, 0);
            }
            Ag += 128; Bg += 128;
            __syncthreads();

            i32x8 bf[4];
#pragma unroll
            for (int j = 0; j < 4; ++j) {
                const int row = wn * 64 + j * 16 + lm;
                const int sw  = (row & 7) << 4;
                const uint8_t* rp = Bs + row * 128;
                i32x4 lo = *(const i32x4*)(rp + (c0 ^ sw));
                i32x4 hi = *(const i32x4*)(rp + (c1 ^ sw));
                bf[j] = __builtin_shufflevector(lo, hi, 0, 1, 2, 3, 4, 5, 6, 7);
            }
#pragma unroll
            for (int i = 0; i < 4; ++i) {
                const int row = wm * 64 + i * 16 + lm;
                const int sw  = (row & 7) << 4;
                const uint8_t* rp = As + row * 128;
                i32x4 lo = *(const i32x4*)(rp + (c0 ^ sw));
                i32x4 hi = *(const i32x4*)(rp + (c1 ^ sw));
                i32x8 af = __builtin_shufflevector(lo, hi, 0, 1, 2, 3, 4, 5, 6, 7);
#pragma unroll
                for (int j = 0; j < 4; ++j)
                    acc[i][j] = __builtin_amdgcn_mfma_scale_f32_16x16x128_f8f6f4(
                        af, bf[j], acc[i][j], 0, 0, 0, 0x7f7f7f7f, 0, 0x7f7f7f7f);
            }
            __syncthreads();
        }
    }

    // undo the WSCALE applied to the fp8 spline weights (in-register)
#pragma unroll
    for (int i = 0; i < 4; ++i)
#pragma unroll
        for (int j = 0; j < 4; ++j)
            acc[i][j] *= (1.0f / WSCALE);

    // ---------------- base bf16 phase (kz==0 blocks only) ----------------
    if (kz == 0) {
        const uint8_t* Ag = Ab + (size_t)(bm * 128 + w * 32 + srow) * (KB * 2) + schunk;
        const uint8_t* Bg = Wb + (size_t)(bn * 128 + w * 32 + srow) * (KB * 2) + schunk;

        for (int ks = 0; ks < (KB * 2) / 128; ++ks) {
#pragma unroll
            for (int j = 0; j < 4; ++j) {
                __builtin_amdgcn_global_load_lds(
                    (const uint32_t*)(Ag + (size_t)(j * 8) * (KB * 2)),
                    (uint32_t*)(As + (w * 32 + j * 8) * 128), 16, 0, 0);
                __builtin_amdgcn_global_load_lds(
                    (const uint32_t*)(Bg + (size_t)(j * 8) * (KB * 2)),
                    (uint32_t*)(Bs + (w * 32 + j * 8) * 128), 16, 0, 0);
            }
            Ag += 128; Bg += 128;
            __syncthreads();

#pragma unroll
            for (int h = 0; h < 2; ++h) {
                bf16x8 af[4], bfr[4];
#pragma unroll
                for (int i = 0; i < 4; ++i) {
                    const int row = wm * 64 + i * 16 + lm;
                    af[i] = *(const bf16x8*)(As + row * 128 + ((((h * 4 + q) ^ (row & 7))) << 4));
                }
#pragma unroll
                for (int j = 0; j < 4; ++j) {
                    const int row = wn * 64 + j * 16 + lm;
                    bfr[j] = *(const bf16x8*)(Bs + row * 128 + ((((h * 4 + q) ^ (row & 7))) << 4));
                }
#pragma unroll
                for (int i = 0; i < 4; ++i)
#pragma unroll
                    for (int j = 0; j < 4; ++j)
                        acc[i][j] = __builtin_amdgcn_mfma_f32_16x16x32_bf16(af[i], bfr[j], acc[i][j], 0, 0, 0);
            }
            __syncthreads();
        }
    }

    // epilogue: C/D layout col = lane&15, row = (lane>>4)*4 + reg
    const int row0 = bm * 128 + wm * 64 + q * 4;
    const int col0 = bn * 128 + wn * 64 + lm;
#pragma unroll
    for (int i = 0; i < 4; ++i)
#pragma unroll
        for (int j = 0; j < 4; ++j)
#pragma unroll
            for (int r = 0; r < 4; ++r)
                unsafeAtomicAdd(&C[(size_t)(row0 + i * 16 + r) * OUT_DIM + col0 + j * 16],
                                acc[i][j][r]);
}

// ---------------------------------------------------------------------------
extern "C" void kernel_launch(void* const* d_in, const int* in_sizes, int n_in,
                              void* d_out, int out_size, void* d_ws, size_t ws_size,
                              hipStream_t stream) {
    const float* x     = (const float*)d_in[0];   // (B, I)
    const float* sb    = (const float*)d_in[1];   // (O, I)
    const float* ss    = (const float*)d_in[2];   // (O, I)
    const float* coeff = (const float*)d_in[3];   // (2, O, I, G)
    float* out = (float*)d_out;                   // (B, O)

    uint8_t* A8 = (uint8_t*)d_ws;                          // 4096*16384 fp8 = 67.1 MB
    uint8_t* W8 = A8 + (size_t)BATCH * K8;                 // 1024*16384 fp8 = 16.8 MB
    __bf16*  Ab = (__bf16*)(W8 + (size_t)OUT_DIM * K8);    // 4096*1024 bf16 = 8.4 MB
    __bf16*  Wb = Ab + (size_t)BATCH * KB;                 // 1024*1024 bf16 = 2.1 MB

    hipLaunchKernelGGL(prep_feat, dim3(BATCH * IN_DIM / 16 / 256), dim3(256), 0, stream,
                       x, A8, Ab, out);
    hipLaunchKernelGGL(prep_w, dim3(OUT_DIM), dim3(256), 0, stream,
                       sb, ss, coeff, W8, Wb);
    hipLaunchKernelGGL(gemm_all, dim3(OUT_DIM / 128, BATCH / 128, SPLIT8), dim3(256), 0, stream,
                       A8, W8, (const uint8_t*)Ab, (const uint8_t*)Wb, out);
}

// Round 4
// 234.995 us; speedup vs baseline: 1.1778x; 1.0143x over previous
//
#include <hip/hip_runtime.h>
#include <hip/hip_bf16.h>
#include <stdint.h>

#define BATCH   4096
#define IN_DIM  1024
#define OUT_DIM 1024
#define GRID_G  8
#define K8      16384            // spline K: 16 planes (8 cos + 8 sin) * 1024
#define KB      1024             // base K (silu plane)
#define SPLIT8  4                // split-K: 4 chunks (spline 32 iters + base 4 iters each)
#define WSCALE  256.0f           // spline weights scaled into e4m3 range

typedef __bf16 bf16x8 __attribute__((ext_vector_type(8)));
typedef __bf16 bf16x4 __attribute__((ext_vector_type(4)));
typedef float  f32x4  __attribute__((ext_vector_type(4)));
typedef int    i32x4  __attribute__((ext_vector_type(4)));
typedef int    i32x8  __attribute__((ext_vector_type(8)));

// ---------------------------------------------------------------------------
// prep (merged r3->r4): blocks [0,1024) = features, [1024,2048) = weight fold.
// One dispatch instead of two: saves a launch gap, and the VALU-heavy feature
// blocks overlap the memory-heavy weight blocks on the same CUs.
//
// feat part: silu(x)->Ab bf16; cos(gx),sin(gx) g=1..8 -> A8 fp8 planes
//            [b, p*1024+i] (p<8 cos, p>=8 sin); zeroes C (coalesced).
// w part:    W8[o,p*1024+i] = ss*coeff*WSCALE fp8; Wb = sb bf16. coeff slab
//            staged through XOR-swizzled LDS (coalesced 4KB loads -> per-thread
//            128B read-back at the b128 bank floor).
// ---------------------------------------------------------------------------
__global__ __launch_bounds__(256) void prep(const float* __restrict__ x,
                                            const float* __restrict__ sb,
                                            const float* __restrict__ ss,
                                            const float* __restrict__ coeff,
                                            uint8_t* __restrict__ A8,
                                            uint8_t* __restrict__ W8,
                                            __bf16* __restrict__ Ab,
                                            __bf16* __restrict__ Wb,
                                            float* __restrict__ C) {
    __shared__ __align__(16) float lds[8192];        // 32 KB (w-branch only)
    const int tid = threadIdx.x;

    if (blockIdx.x < 1024) {
        // ---------------- features ----------------
        const int t  = blockIdx.x * 256 + tid;       // over B*I/16
        const int b  = t >> 6;
        const int i0 = (t & 63) * 16;

        // zero C: block covers a contiguous 16 KB region
        {
            float4 z = make_float4(0.f, 0.f, 0.f, 0.f);
            float4* cz = (float4*)(C + (size_t)blockIdx.x * 4096);
#pragma unroll
            for (int j = 0; j < 4; ++j) cz[j * 256 + tid] = z;
        }

        float xv[16];
        {
            const float4* xp = (const float4*)(x + (size_t)b * IN_DIM + i0);
            float4 q0 = xp[0], q1 = xp[1], q2 = xp[2], q3 = xp[3];
            xv[0]=q0.x;  xv[1]=q0.y;  xv[2]=q0.z;  xv[3]=q0.w;
            xv[4]=q1.x;  xv[5]=q1.y;  xv[6]=q1.z;  xv[7]=q1.w;
            xv[8]=q2.x;  xv[9]=q2.y;  xv[10]=q2.z; xv[11]=q2.w;
            xv[12]=q3.x; xv[13]=q3.y; xv[14]=q3.z; xv[15]=q3.w;
        }

        float c1[16], s1[16], ck[16], sk[16];
        bf16x8 va, vb;
#pragma unroll
        for (int j = 0; j < 16; ++j) {
            float e  = __expf(-xv[j]);
            float sl = xv[j] * __builtin_amdgcn_rcpf(1.f + e);
            if (j < 8) va[j & 7] = (__bf16)sl; else vb[j & 7] = (__bf16)sl;
            s1[j] = __sinf(xv[j]);
            c1[j] = __cosf(xv[j]);
            ck[j] = c1[j]; sk[j] = s1[j];
        }
        *(bf16x8*)(Ab + (size_t)b * IN_DIM + i0)     = va;
        *(bf16x8*)(Ab + (size_t)b * IN_DIM + i0 + 8) = vb;

        uint8_t* a8 = A8 + (size_t)b * K8 + i0;
#pragma unroll
        for (int g = 0; g < GRID_G; ++g) {
            i32x4 wc, ws;
#pragma unroll
            for (int q = 0; q < 4; ++q) {
                int dc = 0, ds = 0;
                dc = __builtin_amdgcn_cvt_pk_fp8_f32(ck[4*q+0], ck[4*q+1], dc, false);
                dc = __builtin_amdgcn_cvt_pk_fp8_f32(ck[4*q+2], ck[4*q+3], dc, true);
                ds = __builtin_amdgcn_cvt_pk_fp8_f32(sk[4*q+0], sk[4*q+1], ds, false);
                ds = __builtin_amdgcn_cvt_pk_fp8_f32(sk[4*q+2], sk[4*q+3], ds, true);
                wc[q] = dc; ws[q] = ds;
            }
            *(i32x4*)(a8 + (size_t)g * IN_DIM)            = wc;
            *(i32x4*)(a8 + (size_t)(GRID_G + g) * IN_DIM) = ws;
            if (g < GRID_G - 1) {
#pragma unroll
                for (int j = 0; j < 16; ++j) {
                    float cn = ck[j] * c1[j] - sk[j] * s1[j];
                    float sn = sk[j] * c1[j] + ck[j] * s1[j];
                    ck[j] = cn; sk[j] = sn;
                }
            }
        }
    } else {
        // ---------------- weight fold (one o-row per block) ----------------
        const int o   = blockIdx.x - 1024;
        const int i0  = tid * 4;
        const size_t oi = (size_t)o * IN_DIM + i0;

        const float4 s4 = *(const float4*)(ss + oi);
        const float  s[4] = {s4.x * WSCALE, s4.y * WSCALE, s4.z * WSCALE, s4.w * WSCALE};

        {
            float4 b4 = *(const float4*)(sb + oi);
            bf16x4 wv;
            wv[0] = (__bf16)b4.x; wv[1] = (__bf16)b4.y;
            wv[2] = (__bf16)b4.z; wv[3] = (__bf16)b4.w;
            *(bf16x4*)(Wb + oi) = wv;
        }

        uint8_t* w8 = W8 + (size_t)o * K8 + i0;
        for (int p = 0; p < 2; ++p) {
            if (p) __syncthreads();                  // protect lds reuse
            const float4* src = (const float4*)(coeff + ((size_t)p * OUT_DIM + o) * (IN_DIM * GRID_G));
#pragma unroll
            for (int j = 0; j < 8; ++j) {
                float4 v = src[j * 256 + tid];       // linear byte L = j*4096 + tid*16
                const int L   = j * 4096 + tid * 16;
                const int row = L >> 7;              // 128-B row
                const int ch  = (L >> 4) & 7;        // 16-B chunk in row
                *(float4*)((uint8_t*)lds + row * 128 + ((ch ^ (row & 7)) << 4)) = v;
            }
            __syncthreads();
            float c[4][8];
            {
                const uint8_t* rp = (const uint8_t*)lds + tid * 128;
                const int r7 = (tid & 7) << 4;
#pragma unroll
                for (int j = 0; j < 8; ++j) {
                    float4 v = *(const float4*)(rp + ((j << 4) ^ r7));
                    c[j >> 1][(j & 1) * 4 + 0] = v.x;
                    c[j >> 1][(j & 1) * 4 + 1] = v.y;
                    c[j >> 1][(j & 1) * 4 + 2] = v.z;
                    c[j >> 1][(j & 1) * 4 + 3] = v.w;
                }
            }
#pragma unroll
            for (int g = 0; g < GRID_G; ++g) {
                int d = 0;
                d = __builtin_amdgcn_cvt_pk_fp8_f32(s[0]*c[0][g], s[1]*c[1][g], d, false);
                d = __builtin_amdgcn_cvt_pk_fp8_f32(s[2]*c[2][g], s[3]*c[3][g], d, true);
                *(int*)(w8 + (size_t)(p * GRID_G + g) * IN_DIM) = d;
            }
        }
    }
}

// ---------------------------------------------------------------------------
// Unified GEMM. Grid (8, 32, 4) = 1024 blocks = exactly 4 blocks/CU resident.
// r3->r4: PERFECT per-block balance — every kz block now runs its spline
// chunk (32 iters fp8 ~138cyc) PLUS a 256-elem slice of the base bf16 GEMM
// (4 iters ~155cyc): 32*138+4*155 ~ 5036 cyc-weight for ALL blocks. Previous
// layout gave kz0 48 iters vs 32 -> each CU spent the last third of its
// timeline at 1/4 TLP. Base split-K is free (epilogue already atomic); the
// 4 co-resident blocks on a CU share the same (bm,bn) C-tile so their
// atomic passes stay L2-local.
// 128x128 tile, 4 waves 2x2, 32 KB LDS, XOR 16B-chunk swizzle (c ^ (row&7))
// on staging global addr -> conflict-free b128 frag reads. XCD-aware (bm,bn)
// swizzle (each XCD owns an 8bm x 4bn sub-grid; FETCH 308->120 MB).
// Epilogue: HW f32 atomic add into zeroed C (proven under graph capture).
// ---------------------------------------------------------------------------
__global__ __launch_bounds__(256, 4) void gemm_all(const uint8_t* __restrict__ A8,
                                                   const uint8_t* __restrict__ W8,
                                                   const uint8_t* __restrict__ Ab,
                                                   const uint8_t* __restrict__ Wb,
                                                   float* __restrict__ C) {
    __shared__ __align__(16) uint8_t As[16384];
    __shared__ __align__(16) uint8_t Bs[16384];
    const int tid = threadIdx.x;
    const int w   = tid >> 6;
    const int l   = tid & 63;
    // XCD swizzle: flat 0..255, xcd = flat&7 (dispatch round-robin model)
    const int flat = blockIdx.y * 8 + blockIdx.x;
    const int xcd  = flat & 7;
    const int idx  = flat >> 3;                   // 0..31 within XCD
    const int bn   = (xcd & 1) * 4 + (idx & 3);   // N/128 = 8
    const int bm   = (xcd >> 1) * 8 + (idx >> 2); // M/128 = 32
    const int kz  = blockIdx.z;                   // 0..3 K-chunks
    const int wm  = w & 1;
    const int wn  = w >> 1;

    f32x4 acc[4][4] = {};

    const int srow   = l >> 3;                  // 0..7
    const int schunk = ((l & 7) ^ srow) * 16;   // byte offset of swizzled 16B chunk
    const int lm = l & 15;
    const int q  = l >> 4;                      // 0..3

    // ---------------- spline fp8 phase (chunk kz) ----------------
    {
        const uint8_t* Ag = A8 + (size_t)(bm * 128 + w * 32 + srow) * K8 + kz * (K8 / SPLIT8) + schunk;
        const uint8_t* Bg = W8 + (size_t)(bn * 128 + w * 32 + srow) * K8 + kz * (K8 / SPLIT8) + schunk;
        const int c0 = (q * 2) << 4, c1 = (q * 2 + 1) << 4;   // lane's two chunk offsets

        for (int ks = 0; ks < (K8 / SPLIT8) / 128; ++ks) {
#pragma unroll
            for (int j = 0; j < 4; ++j) {
                __builtin_amdgcn_global_load_lds(
                    (const uint32_t*)(Ag + (size_t)(j * 8) * K8),
                    (uint32_t*)(As + (w * 32 + j * 8) * 128), 16, 0, 0);
                __builtin_amdgcn_global_load_lds(
                    (const uint32_t*)(Bg + (size_t)(j * 8) * K8),
                    (uint32_t*)(Bs + (w * 32 + j * 8) * 128), 16, 0, 0);
            }
            Ag += 128; Bg += 128;
            __syncthreads();

            i32x8 bf[4];
#pragma unroll
            for (int j = 0; j < 4; ++j) {
                const int row = wn * 64 + j * 16 + lm;
                const int sw  = (row & 7) << 4;
                const uint8_t* rp = Bs + row * 128;
                i32x4 lo = *(const i32x4*)(rp + (c0 ^ sw));
                i32x4 hi = *(const i32x4*)(rp + (c1 ^ sw));
                bf[j] = __builtin_shufflevector(lo, hi, 0, 1, 2, 3, 4, 5, 6, 7);
            }
#pragma unroll
            for (int i = 0; i < 4; ++i) {
                const int row = wm * 64 + i * 16 + lm;
                const int sw  = (row & 7) << 4;
                const uint8_t* rp = As + row * 128;
                i32x4 lo = *(const i32x4*)(rp + (c0 ^ sw));
                i32x4 hi = *(const i32x4*)(rp + (c1 ^ sw));
                i32x8 af = __builtin_shufflevector(lo, hi, 0, 1, 2, 3, 4, 5, 6, 7);
#pragma unroll
                for (int j = 0; j < 4; ++j)
                    acc[i][j] = __builtin_amdgcn_mfma_scale_f32_16x16x128_f8f6f4(
                        af, bf[j], acc[i][j], 0, 0, 0, 0x7f7f7f7f, 0, 0x7f7f7f7f);
            }
            __syncthreads();
        }
    }

    // undo the WSCALE applied to the fp8 spline weights (in-register)
#pragma unroll
    for (int i = 0; i < 4; ++i)
#pragma unroll
        for (int j = 0; j < 4; ++j)
            acc[i][j] *= (1.0f / WSCALE);

    // ---------------- base bf16 phase: K-slice kz (256 elems, 4 iters) -----
    {
        const uint8_t* Ag = Ab + (size_t)(bm * 128 + w * 32 + srow) * (KB * 2) + kz * 512 + schunk;
        const uint8_t* Bg = Wb + (size_t)(bn * 128 + w * 32 + srow) * (KB * 2) + kz * 512 + schunk;

        for (int ks = 0; ks < 4; ++ks) {
#pragma unroll
            for (int j = 0; j < 4; ++j) {
                __builtin_amdgcn_global_load_lds(
                    (const uint32_t*)(Ag + (size_t)(j * 8) * (KB * 2)),
                    (uint32_t*)(As + (w * 32 + j * 8) * 128), 16, 0, 0);
                __builtin_amdgcn_global_load_lds(
                    (const uint32_t*)(Bg + (size_t)(j * 8) * (KB * 2)),
                    (uint32_t*)(Bs + (w * 32 + j * 8) * 128), 16, 0, 0);
            }
            Ag += 128; Bg += 128;
            __syncthreads();

#pragma unroll
            for (int h = 0; h < 2; ++h) {
                bf16x8 af[4], bfr[4];
#pragma unroll
                for (int i = 0; i < 4; ++i) {
                    const int row = wm * 64 + i * 16 + lm;
                    af[i] = *(const bf16x8*)(As + row * 128 + ((((h * 4 + q) ^ (row & 7))) << 4));
                }
#pragma unroll
                for (int j = 0; j < 4; ++j) {
                    const int row = wn * 64 + j * 16 + lm;
                    bfr[j] = *(const bf16x8*)(Bs + row * 128 + ((((h * 4 + q) ^ (row & 7))) << 4));
                }
#pragma unroll
                for (int i = 0; i < 4; ++i)
#pragma unroll
                    for (int j = 0; j < 4; ++j)
                        acc[i][j] = __builtin_amdgcn_mfma_f32_16x16x32_bf16(af[i], bfr[j], acc[i][j], 0, 0, 0);
            }
            __syncthreads();
        }
    }

    // epilogue: C/D layout col = lane&15, row = (lane>>4)*4 + reg
    const int row0 = bm * 128 + wm * 64 + q * 4;
    const int col0 = bn * 128 + wn * 64 + lm;
#pragma unroll
    for (int i = 0; i < 4; ++i)
#pragma unroll
        for (int j = 0; j < 4; ++j)
#pragma unroll
            for (int r = 0; r < 4; ++r)
                unsafeAtomicAdd(&C[(size_t)(row0 + i * 16 + r) * OUT_DIM + col0 + j * 16],
                                acc[i][j][r]);
}

// ---------------------------------------------------------------------------
extern "C" void kernel_launch(void* const* d_in, const int* in_sizes, int n_in,
                              void* d_out, int out_size, void* d_ws, size_t ws_size,
                              hipStream_t stream) {
    const float* x     = (const float*)d_in[0];   // (B, I)
    const float* sb    = (const float*)d_in[1];   // (O, I)
    const float* ss    = (const float*)d_in[2];   // (O, I)
    const float* coeff = (const float*)d_in[3];   // (2, O, I, G)
    float* out = (float*)d_out;                   // (B, O)

    uint8_t* A8 = (uint8_t*)d_ws;                          // 4096*16384 fp8 = 67.1 MB
    uint8_t* W8 = A8 + (size_t)BATCH * K8;                 // 1024*16384 fp8 = 16.8 MB
    __bf16*  Ab = (__bf16*)(W8 + (size_t)OUT_DIM * K8);    // 4096*1024 bf16 = 8.4 MB
    __bf16*  Wb = Ab + (size_t)BATCH * KB;                 // 1024*1024 bf16 = 2.1 MB

    hipLaunchKernelGGL(prep, dim3(2048), dim3(256), 0, stream,
                       x, sb, ss, coeff, A8, W8, Ab, Wb, out);
    hipLaunchKernelGGL(gemm_all, dim3(OUT_DIM / 128, BATCH / 128, SPLIT8), dim3(256), 0, stream,
                       A8, W8, (const uint8_t*)Ab, (const uint8_t*)Wb, out);
}